// Round 5
// baseline (293.914 us; speedup 1.0000x reference)
//
#include <hip/hip_runtime.h>
#include <hip/hip_cooperative_groups.h>
#include <cstdint>
#include <cstddef>

namespace cg = cooperative_groups;

// Mask R-CNN detection post-processing, ONE cooperative dispatch (324 x 256):
//   P1 (blocks 0..161, 2/class): u64-key stable rank + sorted boxes -> global
//   P2 (all 324, class x word-pair {wp,7-wp}): IoU suppression bitmatrix
//   P3 (blocks 0..80): LDS-staged wave-cooperative greedy sweep + top-300 cut
//   P4 (last ticket block): per-row max/first-argmax + u64-key top-100 + output
// Stable sorts via integer keys (scores >= 0 from softmax => raw-bit monotone):
//   key = (~bits(s) << 32) | index; ascending key == argsort(-s) exactly.
// IoU uses IEEE f32 division in reference expression order (absmax 0.0, R1-R4).

#define R 512
#define K 81
#define IM_W_MAX 1332.0f   // IM_W - 1
#define IM_H_MAX 799.0f    // IM_H - 1
#define XFORM_CLIP_F 4.135166556742356f  // log(1000/16)
#define NMS_THRESH_F 0.5f
#define SCORE_THRESH_F 0.001f
#define MAX_PER_IMG 100
#define POST_NMS_TOPN 300

// Box transform for (roi r, class k), original deltas layout. Arithmetic
// value-identical to rounds 1-4 (verified absmax 0.0). 16B-aligned loads:
// byte offset 1296r + 16k == 0 mod 16.
__device__ __forceinline__ float4 transform_box(const float* __restrict__ rois,
                                                const float* __restrict__ deltas,
                                                int r, int k) {
    float4 roi = ((const float4*)rois)[r];
    float4 d4  = *(const float4*)(deltas + (size_t)r * (4 * K) + 4 * k);
    float w  = roi.z - roi.x + 1.0f;
    float h  = roi.w - roi.y + 1.0f;
    float cx = roi.x + 0.5f * w;
    float cy = roi.y + 0.5f * h;
    float dx = d4.x / 10.0f;                       // WX
    float dy = d4.y / 10.0f;                       // WY
    float dw = fminf(d4.z / 5.0f, XFORM_CLIP_F);   // WW
    float dh = fminf(d4.w / 5.0f, XFORM_CLIP_F);   // WH
    float pcx = dx * w + cx;
    float pcy = dy * h + cy;
    float pw  = expf(dw) * w;
    float ph  = expf(dh) * h;
    float4 b;
    b.x = fminf(fmaxf(pcx - 0.5f * pw, 0.0f), IM_W_MAX);
    b.y = fminf(fmaxf(pcy - 0.5f * ph, 0.0f), IM_H_MAX);
    b.z = fminf(fmaxf(pcx + 0.5f * pw - 1.0f, 0.0f), IM_W_MAX);
    b.w = fminf(fmaxf(pcy + 0.5f * ph - 1.0f, 0.0f), IM_H_MAX);
    return b;
}

__global__ void __launch_bounds__(256)
detect_all(const float* __restrict__ rois,
           const float* __restrict__ deltas,
           const float* __restrict__ scores,
           float4* __restrict__ sbox_g,              // [K][R] sorted boxes
           int* __restrict__ order_g,                // [K][R] order[rank]=orig
           float* __restrict__ ssc_g,                // [K][R] sorted scores
           int* __restrict__ valid_g,                // [K]
           unsigned long long* __restrict__ supT_g,  // [K][8][512]
           float* __restrict__ dists_t,              // [K][R]
           unsigned int* __restrict__ ticket,
           float* __restrict__ out) {
    cg::grid_group grid = cg::this_grid();
    const int b   = blockIdx.x;
    const int tid = threadIdx.x;

    // 32 KB phase-overlaid LDS buffer.
    __shared__ char s_buf[32768] __attribute__((aligned(16)));
    unsigned long long* s_key  = (unsigned long long*)s_buf;        // P1/P4: 4 KB
    int*                s_arg  = (int*)(s_buf + 4096);              // P4:    2 KB
    float4*             s_sbox = (float4*)s_buf;                    // P2:    8 KB
    float*              s_area = (float*)(s_buf + 8192);            // P2:    2 KB
    unsigned long long* s_supT = (unsigned long long*)s_buf;        // P3:   32 KB
    __shared__ float s_red[256];
    __shared__ unsigned long long s_keep[8];
    __shared__ int s_last;

    // ===== P1: per-class stable rank + sorted boxes (blocks 0..161) =====
    if (b < 2 * K) {
        const int k = b >> 1, half = b & 1;
        float m = -1.0f;
        for (int j = tid; j < R; j += 256) {
            float sc = scores[j * K + k];
            unsigned int bits = __float_as_uint(sc);   // sc >= 0: bits monotone
            s_key[j] = ((unsigned long long)(~bits) << 32) | (unsigned int)j;
            m = fmaxf(m, sc);
        }
        s_red[tid] = m;
        __syncthreads();
        for (int s = 128; s > 0; s >>= 1) {
            if (tid < s) s_red[tid] = fmaxf(s_red[tid], s_red[tid + s]);
            __syncthreads();
        }
        const bool valid = (k != 0) && (s_red[0] > SCORE_THRESH_F);  // uniform
        if (tid == 0 && half == 0) valid_g[k] = valid;
        if (valid) {
            const int ri = half * 256 + tid;          // this thread's roi
            const unsigned long long ki = s_key[ri];
            int cnt = 0;                               // exact stable rank
            const ulonglong2* kp = (const ulonglong2*)s_key;
            #pragma unroll 8
            for (int j2 = 0; j2 < R / 2; ++j2) {
                ulonglong2 k2 = kp[j2];
                cnt += (k2.x < ki);
                cnt += (k2.y < ki);
            }
            float sc = __uint_as_float(~(unsigned int)(ki >> 32));
            sbox_g[k * R + cnt]  = transform_box(rois, deltas, ri, k);
            order_g[k * R + cnt] = ri;
            ssc_g[k * R + cnt]   = sc;
        }
    }
    __threadfence();
    grid.sync();

    // ===== P2: bitmatrix (all 324 blocks; k = b/4, words {wp, 7-wp}) =====
    {
        const int k = b >> 2, wp = b & 3;
        if (valid_g[k]) {
            for (int i = tid; i < R; i += 256) {
                float4 bx = sbox_g[k * R + i];
                s_sbox[i] = bx;
                s_area[i] = (bx.z - bx.x + 1.0f) * (bx.w - bx.y + 1.0f);
            }
            __syncthreads();
            #pragma unroll
            for (int t = 0; t < 2; ++t) {
                const int w = t ? (7 - wp) : wp;      // balanced: rows sum 576
                const int jbase = w * 64;
                for (int i = tid; i < R; i += 256) {
                    const int d = i - jbase;          // bits jj <= d are j <= i
                    unsigned long long mask =
                        (d < 0) ? ~0ull : ((d >= 63) ? 0ull : (~0ull << (d + 1)));
                    unsigned long long bits = 0ull;
                    if (mask) {                       // wave-uniform skip
                        const float4 bi = s_sbox[i];
                        const float  ai = s_area[i];
                        #pragma unroll 8
                        for (int jj = 0; jj < 64; ++jj) {
                            float4 bj = s_sbox[jbase + jj];   // broadcast read
                            float  aj = s_area[jbase + jj];
                            float xx1 = fmaxf(bi.x, bj.x);
                            float yy1 = fmaxf(bi.y, bj.y);
                            float xx2 = fminf(bi.z, bj.z);
                            float yy2 = fminf(bi.w, bj.w);
                            float iw = fmaxf(xx2 - xx1 + 1.0f, 0.0f);
                            float ih = fmaxf(yy2 - yy1 + 1.0f, 0.0f);
                            float inter = iw * ih;
                            float iou = inter / (ai + aj - inter); // IEEE div
                            bits |= (unsigned long long)(iou > NMS_THRESH_F) << jj;
                        }
                    }
                    supT_g[k * 4096 + w * 512 + i] = bits & mask;
                }
            }
        }
    }
    __threadfence();
    grid.sync();
    if (b >= K) return;

    // ===== P3: sweep (blocks 0..80) =====
    const int k3 = b;
    if (valid_g[k3]) {
        {   // stage 32 KB bitmatrix to LDS, coalesced 16B
            const ulonglong2* src = (const ulonglong2*)(supT_g + (size_t)k3 * 4096);
            ulonglong2* dst = (ulonglong2*)s_supT;
            #pragma unroll
            for (int t = 0; t < 8; ++t) dst[tid + t * 256] = src[tid + t * 256];
        }
        __syncthreads();
        if (tid < 64) {                    // R3/R4-verified sweep, verbatim
            const int l = tid;
            unsigned long long kb[8];
            #pragma unroll
            for (int w = 0; w < 8; ++w) kb[w] = ~0ull;
            #pragma unroll
            for (int wb = 0; wb < 8; ++wb) {
                unsigned long long rrow[8];
                #pragma unroll
                for (int w = 0; w < 8; ++w)
                    rrow[w] = (w >= wb) ? s_supT[w * R + (wb * 64 + l)] : 0ull;
                const unsigned int r_lo = (unsigned int)(rrow[wb] & 0xffffffffull);
                const unsigned int r_hi = (unsigned int)(rrow[wb] >> 32);
                unsigned long long cur = kb[wb];
                unsigned long long m = cur;
                while (m) {                // intra-block greedy, wave-uniform
                    int bit = __builtin_ctzll(m);
                    unsigned long long row =
                        ((unsigned long long)(unsigned int)__builtin_amdgcn_readlane((int)r_hi, bit) << 32) |
                         (unsigned long long)(unsigned int)__builtin_amdgcn_readlane((int)r_lo, bit);
                    m &= m - 1;
                    cur &= ~row;
                    m   &= ~row;
                }
                kb[wb] = cur;
                #pragma unroll
                for (int w = wb + 1; w < 8; ++w) {   // inter-block pruning
                    unsigned long long contrib = ((cur >> l) & 1ull) ? rrow[w] : 0ull;
                    #pragma unroll
                    for (int off = 32; off > 0; off >>= 1)
                        contrib |= __shfl_xor(contrib, off, 64);
                    kb[w] &= ~contrib;
                }
            }
            int total = 0;                 // cumsum(keep) <= 300 cut
            #pragma unroll
            for (int w = 0; w < 8; ++w) total += __popcll(kb[w]);
            if (total > POST_NMS_TOPN) {
                int cnt = 0;
                #pragma unroll
                for (int w = 0; w < 8; ++w) {
                    int pc = __popcll(kb[w]);
                    if (cnt + pc <= POST_NMS_TOPN) { cnt += pc; continue; }
                    unsigned long long word = kb[w], outw = 0ull;
                    int room = POST_NMS_TOPN - cnt;
                    while (room > 0) {
                        unsigned long long lsb = word & (~word + 1ull);
                        outw |= lsb; word ^= lsb; --room;
                    }
                    kb[w] = outw; cnt = POST_NMS_TOPN;
                }
            }
            if (l == 0) {
                #pragma unroll
                for (int w = 0; w < 8; ++w) s_keep[w] = kb[w];
            }
        }
        __syncthreads();
        for (int rk = tid; rk < R; rk += 256) {
            bool kept = (s_keep[rk >> 6] >> (rk & 63)) & 1ull;
            dists_t[k3 * R + order_g[k3 * R + rk]] = kept ? ssc_g[k3 * R + rk] : 0.0f;
        }
    } else {
        for (int i = tid; i < R; i += 256) dists_t[k3 * R + i] = 0.0f;
    }

    // ===== last-block ticket -> P4 finalize (R3-proven pattern) =====
    __syncthreads();
    if (tid == 0) {
        __threadfence();
        unsigned int t = atomicAdd(ticket, 1u);
        s_last = (t == K - 1);
    }
    __syncthreads();
    if (!s_last) return;
    __threadfence();

    for (int rr = tid; rr < R; rr += 256) {
        float vmax = dists_t[rr];          // kk = 0 column (always zeros)
        int arg = 0;
        #pragma unroll 8
        for (int kk = 1; kk < K; ++kk) {
            float v = dists_t[kk * R + rr];
            if (v > vmax) { vmax = v; arg = kk; }   // first-occurrence argmax
        }
        unsigned int bits = __float_as_uint(vmax);  // vmax >= 0
        s_key[rr] = ((unsigned long long)(~bits) << 32) | (unsigned int)rr;
        s_arg[rr] = arg;
    }
    __syncthreads();
    for (int rr = tid; rr < R; rr += 256) {
        const unsigned long long ki = s_key[rr];
        int cnt = 0;                       // exact stable rank
        const ulonglong2* kp = (const ulonglong2*)s_key;
        #pragma unroll 8
        for (int j2 = 0; j2 < R / 2; ++j2) {
            ulonglong2 k2 = kp[j2];
            cnt += (k2.x < ki);
            cnt += (k2.y < ki);
        }
        if (cnt < MAX_PER_IMG) {
            float vmax = __uint_as_float(~(unsigned int)(ki >> 32));
            int arg = s_arg[rr];
            bool valid = vmax > SCORE_THRESH_F;
            float4 bx = transform_box(rois, deltas, rr, arg);
            out[cnt * 5 + 0] = valid ? vmax : 0.0f;
            out[cnt * 5 + 1] = valid ? bx.x : 0.0f;
            out[cnt * 5 + 2] = valid ? bx.y : 0.0f;
            out[cnt * 5 + 3] = valid ? bx.z : 0.0f;
            out[cnt * 5 + 4] = valid ? bx.w : 0.0f;
            out[500 + cnt] = (float)arg;   // labels_all
            out[600 + cnt] = (float)rr;    // top
        }
    }
}

// ---------------------------------------------------------------------------
extern "C" void kernel_launch(void* const* d_in, const int* in_sizes, int n_in,
                              void* d_out, int out_size, void* d_ws, size_t ws_size,
                              hipStream_t stream) {
    const float* rois   = (const float*)d_in[0];   // [512,4]
    const float* deltas = (const float*)d_in[1];   // [512,324]
    const float* scores = (const float*)d_in[2];   // [512,81]
    float* out = (float*)d_out;                    // 700 floats

    char* ws = (char*)d_ws;                        // ~3.7 MB used
    float4* sbox_g  = (float4*)(ws + 0);                              // 663,552 B
    int*    order_g = (int*)   (ws + 663552);                         // 165,888 B
    float*  ssc_g   = (float*) (ws + 829440);                         // 165,888 B
    int*    valid_g = (int*)   (ws + 995328);                         //     512 B
    float*  dists_t = (float*) (ws + 995840);                         // 165,888 B
    unsigned long long* supT_g = (unsigned long long*)(ws + 1161728); // 2,654,208 B
    unsigned int* ticket = (unsigned int*)(ws + 3815936);             //       4 B

    hipMemsetAsync(ticket, 0, sizeof(unsigned int), stream);          // ws poisoned

    void* args[] = { (void*)&rois, (void*)&deltas, (void*)&scores,
                     (void*)&sbox_g, (void*)&order_g, (void*)&ssc_g,
                     (void*)&valid_g, (void*)&supT_g, (void*)&dists_t,
                     (void*)&ticket, (void*)&out };
    hipLaunchCooperativeKernel(reinterpret_cast<void*>(detect_all),
                               dim3(324), dim3(256), args, 0, stream);
}

// Round 6
// 150.993 us; speedup vs baseline: 1.9465x; 1.9465x over previous
//
#include <hip/hip_runtime.h>
#include <cstdint>
#include <cstddef>

// Mask R-CNN detection post-processing, 3 stream-ordered kernels (+4B memset):
//   1. rank_boxes (81 x 512):  u64-key stable rank + sorted boxes + validity
//   2. bitmatrix  (648 x 256): IoU suppression bits (class x word) -> global
//   3. sweep      (81 x 256):  LDS-staged wave-cooperative greedy sweep with
//                              ballot fast-paths + top-300 cut + masked scatter;
//                              last-ticket block runs finalize (per-row max/
//                              first-argmax + u64-key stable top-100 + output).
// Stable sorts via integer keys (softmax scores >= 0 => raw-bit monotone):
//   key = (~bits(s) << 32) | index; ascending key == argsort(-s) exactly
//   (bit-exactness verified R5, absmax 0.0).
// IoU uses IEEE f32 division in reference expression order (absmax 0.0 R1-R5).
// NO cooperative launch: grid.sync measured ~+100us regression in R5.

#define R 512
#define K 81
#define IM_W_MAX 1332.0f   // IM_W - 1
#define IM_H_MAX 799.0f    // IM_H - 1
#define XFORM_CLIP_F 4.135166556742356f  // log(1000/16)
#define NMS_THRESH_F 0.5f
#define SCORE_THRESH_F 0.001f
#define MAX_PER_IMG 100
#define POST_NMS_TOPN 300

// Box transform for (roi r, class k), original deltas layout. Arithmetic
// value-identical to rounds 1-5 (verified absmax 0.0). 16B-aligned loads.
__device__ __forceinline__ float4 transform_box(const float* __restrict__ rois,
                                                const float* __restrict__ deltas,
                                                int r, int k) {
    float4 roi = ((const float4*)rois)[r];
    float4 d4  = *(const float4*)(deltas + (size_t)r * (4 * K) + 4 * k);
    float w  = roi.z - roi.x + 1.0f;
    float h  = roi.w - roi.y + 1.0f;
    float cx = roi.x + 0.5f * w;
    float cy = roi.y + 0.5f * h;
    float dx = d4.x / 10.0f;                       // WX
    float dy = d4.y / 10.0f;                       // WY
    float dw = fminf(d4.z / 5.0f, XFORM_CLIP_F);   // WW
    float dh = fminf(d4.w / 5.0f, XFORM_CLIP_F);   // WH
    float pcx = dx * w + cx;
    float pcy = dy * h + cy;
    float pw  = expf(dw) * w;
    float ph  = expf(dh) * h;
    float4 b;
    b.x = fminf(fmaxf(pcx - 0.5f * pw, 0.0f), IM_W_MAX);
    b.y = fminf(fmaxf(pcy - 0.5f * ph, 0.0f), IM_H_MAX);
    b.z = fminf(fmaxf(pcx + 0.5f * pw - 1.0f, 0.0f), IM_W_MAX);
    b.w = fminf(fmaxf(pcy + 0.5f * ph - 1.0f, 0.0f), IM_H_MAX);
    return b;
}

// ---------------------------------------------------------------------------
// 1. Per-class u64-key stable rank + sorted boxes/scores + validity.
// ---------------------------------------------------------------------------
__global__ void __launch_bounds__(512)
rank_boxes_kernel(const float* __restrict__ rois,
                  const float* __restrict__ deltas,
                  const float* __restrict__ scores,
                  float4* __restrict__ sbox_g,     // [K][R] sorted boxes
                  int* __restrict__ order_g,       // [K][R] order[rank]=orig
                  float* __restrict__ ssc_g,       // [K][R] sorted scores
                  int* __restrict__ valid_g) {     // [K]
    const int k = blockIdx.x, tid = threadIdx.x;
    __shared__ unsigned long long s_key[R];        // 4 KB
    __shared__ float s_red[R];                     // 2 KB

    const float sc = scores[tid * K + k];          // strided, L2-resident
    {
        unsigned int bits = __float_as_uint(sc);   // sc >= 0: bits monotone
        s_key[tid] = ((unsigned long long)(~bits) << 32) | (unsigned int)tid;
    }
    s_red[tid] = sc;
    __syncthreads();
    for (int s = 256; s > 0; s >>= 1) {
        if (tid < s) s_red[tid] = fmaxf(s_red[tid], s_red[tid + s]);
        __syncthreads();
    }
    const bool valid = (k != 0) && (s_red[0] > SCORE_THRESH_F);  // uniform
    if (tid == 0) valid_g[k] = valid;
    if (!valid) return;

    const unsigned long long ki = s_key[tid];
    int cnt = 0;                                   // exact stable rank
    const ulonglong2* kp = (const ulonglong2*)s_key;
    #pragma unroll 8
    for (int j2 = 0; j2 < R / 2; ++j2) {
        ulonglong2 k2 = kp[j2];
        cnt += (k2.x < ki);
        cnt += (k2.y < ki);
    }
    sbox_g[k * R + cnt]  = transform_box(rois, deltas, tid, k);
    order_g[k * R + cnt] = tid;
    ssc_g[k * R + cnt]   = sc;
}

// ---------------------------------------------------------------------------
// 2. Bitmatrix: block = (class k, word w). supT_g[k][w][i] bit jj set iff
//    j = w*64+jj > i and IoU(i,j) > 0.5 (sorted order). 648 blocks.
// ---------------------------------------------------------------------------
__global__ void __launch_bounds__(256)
bitmatrix_kernel(const float4* __restrict__ sbox_g,
                 const int* __restrict__ valid_g,
                 unsigned long long* __restrict__ supT_g) {
    const int b = blockIdx.x;
    const int k = b >> 3;
    const int w = b & 7;
    const int tid = threadIdx.x;
    if (!valid_g[k]) return;       // sweep exits for invalid k too

    __shared__ float4 s_sbox[R];   // 8 KB
    __shared__ float  s_area[R];   // 2 KB
    for (int i = tid; i < R; i += 256) {
        float4 bx = sbox_g[k * R + i];
        s_sbox[i] = bx;
        s_area[i] = (bx.z - bx.x + 1.0f) * (bx.w - bx.y + 1.0f);
    }
    __syncthreads();

    const int jbase = w * 64;
    #pragma unroll
    for (int rep = 0; rep < 2; ++rep) {
        const int i = tid + rep * 256;
        const int d = i - jbase;   // bits jj <= d are j <= i: masked out
        unsigned long long mask =
            (d < 0) ? ~0ull : ((d >= 63) ? 0ull : (~0ull << (d + 1)));
        unsigned long long bits = 0ull;
        if (mask) {                // wave-uniform skip for fully-past waves
            const float4 bi = s_sbox[i];
            const float  ai = s_area[i];
            #pragma unroll 8
            for (int jj = 0; jj < 64; ++jj) {
                float4 bj = s_sbox[jbase + jj];   // broadcast LDS read
                float  aj = s_area[jbase + jj];
                float xx1 = fmaxf(bi.x, bj.x);
                float yy1 = fmaxf(bi.y, bj.y);
                float xx2 = fminf(bi.z, bj.z);
                float yy2 = fminf(bi.w, bj.w);
                float iw = fmaxf(xx2 - xx1 + 1.0f, 0.0f);
                float ih = fmaxf(yy2 - yy1 + 1.0f, 0.0f);
                float inter = iw * ih;
                float iou = inter / (ai + aj - inter);   // IEEE div, ref order
                bits |= (unsigned long long)(iou > NMS_THRESH_F) << jj;
            }
        }
        supT_g[k * 4096 + w * 512 + i] = bits & mask;    // coalesced u64 write
    }
}

// ---------------------------------------------------------------------------
// 3. Sweep + ticket-fused finalize.
// ---------------------------------------------------------------------------
__global__ void __launch_bounds__(256)
sweep_finalize_kernel(const unsigned long long* __restrict__ supT_g,
                      const int* __restrict__ order_g,
                      const float* __restrict__ ssc_g,
                      const int* __restrict__ valid_g,
                      const float* __restrict__ rois,
                      const float* __restrict__ deltas,
                      float* __restrict__ dists_t,     // [K][R]
                      unsigned int* __restrict__ ticket,
                      float* __restrict__ out) {
    const int k = blockIdx.x, tid = threadIdx.x;
    __shared__ unsigned long long s_supT[8 * R];       // 32 KB
    __shared__ unsigned long long s_keep[8];
    __shared__ unsigned long long s_key[R];            // finalize: 4 KB
    __shared__ int  s_arg[R];                          // finalize: 2 KB
    __shared__ int  s_last;

    if (valid_g[k]) {
        {   // stage 32 KB bitmatrix to LDS, coalesced 16B (R4-proven)
            const ulonglong2* src = (const ulonglong2*)(supT_g + (size_t)k * 4096);
            ulonglong2* dst = (ulonglong2*)s_supT;
            #pragma unroll
            for (int t = 0; t < 8; ++t) dst[tid + t * 256] = src[tid + t * 256];
        }
        __syncthreads();
        if (tid < 64) {                    // R3/R4-verified sweep + ballot skips
            const int l = tid;
            unsigned long long kb[8];
            #pragma unroll
            for (int w = 0; w < 8; ++w) kb[w] = ~0ull;
            #pragma unroll
            for (int wb = 0; wb < 8; ++wb) {
                unsigned long long rrow[8];
                #pragma unroll
                for (int w = 0; w < 8; ++w)
                    rrow[w] = (w >= wb) ? s_supT[w * R + (wb * 64 + l)] : 0ull;

                // Intra-block greedy: skip entirely if no suppression bits.
                if (__ballot(rrow[wb] != 0ull)) {
                    const unsigned int r_lo = (unsigned int)(rrow[wb] & 0xffffffffull);
                    const unsigned int r_hi = (unsigned int)(rrow[wb] >> 32);
                    unsigned long long cur = kb[wb];
                    unsigned long long m = cur;
                    while (m) {            // wave-uniform serial sweep
                        int bit = __builtin_ctzll(m);
                        unsigned long long row =
                            ((unsigned long long)(unsigned int)__builtin_amdgcn_readlane((int)r_hi, bit) << 32) |
                             (unsigned long long)(unsigned int)__builtin_amdgcn_readlane((int)r_lo, bit);
                        m &= m - 1;
                        cur &= ~row;
                        m   &= ~row;
                    }
                    kb[wb] = cur;
                }
                // Inter-block pruning; skip empty words (common, sparse data).
                #pragma unroll
                for (int w = wb + 1; w < 8; ++w) {
                    unsigned long long contrib =
                        ((kb[wb] >> l) & 1ull) ? rrow[w] : 0ull;
                    if (__ballot(contrib != 0ull)) {
                        #pragma unroll
                        for (int off = 32; off > 0; off >>= 1)
                            contrib |= __shfl_xor(contrib, off, 64);
                        kb[w] &= ~contrib;
                    }
                }
            }
            int total = 0;                 // cumsum(keep) <= 300 cut
            #pragma unroll
            for (int w = 0; w < 8; ++w) total += __popcll(kb[w]);
            if (total > POST_NMS_TOPN) {
                int cnt = 0;
                #pragma unroll
                for (int w = 0; w < 8; ++w) {
                    int pc = __popcll(kb[w]);
                    if (cnt + pc <= POST_NMS_TOPN) { cnt += pc; continue; }
                    unsigned long long word = kb[w], outw = 0ull;
                    int room = POST_NMS_TOPN - cnt;
                    while (room > 0) {
                        unsigned long long lsb = word & (~word + 1ull);
                        outw |= lsb; word ^= lsb; --room;
                    }
                    kb[w] = outw; cnt = POST_NMS_TOPN;
                }
            }
            if (l == 0) {
                #pragma unroll
                for (int w = 0; w < 8; ++w) s_keep[w] = kb[w];
            }
        }
        __syncthreads();
        for (int rk = tid; rk < R; rk += 256) {
            bool kept = (s_keep[rk >> 6] >> (rk & 63)) & 1ull;
            dists_t[k * R + order_g[k * R + rk]] = kept ? ssc_g[k * R + rk] : 0.0f;
        }
    } else {
        for (int i = tid; i < R; i += 256) dists_t[k * R + i] = 0.0f;
    }

    // ---- last-block ticket -> finalize (R3-proven pattern) ----
    __syncthreads();
    if (tid == 0) {
        __threadfence();                   // release dists_t
        unsigned int t = atomicAdd(ticket, 1u);
        s_last = (t == K - 1);
    }
    __syncthreads();
    if (!s_last) return;
    __threadfence();                       // acquire others' dists_t

    for (int rr = tid; rr < R; rr += 256) {
        float vmax = dists_t[rr];          // kk = 0 column (always zeros)
        int arg = 0;
        #pragma unroll 8
        for (int kk = 1; kk < K; ++kk) {
            float v = dists_t[kk * R + rr];          // coalesced
            if (v > vmax) { vmax = v; arg = kk; }    // first-occurrence argmax
        }
        unsigned int bits = __float_as_uint(vmax);   // vmax >= 0
        s_key[rr] = ((unsigned long long)(~bits) << 32) | (unsigned int)rr;
        s_arg[rr] = arg;
    }
    __syncthreads();
    for (int rr = tid; rr < R; rr += 256) {
        const unsigned long long ki = s_key[rr];
        int cnt = 0;                       // exact stable rank
        const ulonglong2* kp = (const ulonglong2*)s_key;
        #pragma unroll 8
        for (int j2 = 0; j2 < R / 2; ++j2) {
            ulonglong2 k2 = kp[j2];
            cnt += (k2.x < ki);
            cnt += (k2.y < ki);
        }
        if (cnt < MAX_PER_IMG) {
            float vmax = __uint_as_float(~(unsigned int)(ki >> 32));
            int arg = s_arg[rr];
            bool valid = vmax > SCORE_THRESH_F;
            float4 bx = transform_box(rois, deltas, rr, arg);
            out[cnt * 5 + 0] = valid ? vmax : 0.0f;
            out[cnt * 5 + 1] = valid ? bx.x : 0.0f;
            out[cnt * 5 + 2] = valid ? bx.y : 0.0f;
            out[cnt * 5 + 3] = valid ? bx.z : 0.0f;
            out[cnt * 5 + 4] = valid ? bx.w : 0.0f;
            out[500 + cnt] = (float)arg;   // labels_all
            out[600 + cnt] = (float)rr;    // top
        }
    }
}

// ---------------------------------------------------------------------------
extern "C" void kernel_launch(void* const* d_in, const int* in_sizes, int n_in,
                              void* d_out, int out_size, void* d_ws, size_t ws_size,
                              hipStream_t stream) {
    const float* rois   = (const float*)d_in[0];   // [512,4]
    const float* deltas = (const float*)d_in[1];   // [512,324]
    const float* scores = (const float*)d_in[2];   // [512,81]
    float* out = (float*)d_out;                    // 700 floats

    char* ws = (char*)d_ws;                        // ~3.7 MB used
    float4* sbox_g  = (float4*)(ws + 0);                              // 663,552 B
    int*    order_g = (int*)   (ws + 663552);                         // 165,888 B
    float*  ssc_g   = (float*) (ws + 829440);                         // 165,888 B
    int*    valid_g = (int*)   (ws + 995328);                         //     512 B
    float*  dists_t = (float*) (ws + 995840);                         // 165,888 B
    unsigned long long* supT_g = (unsigned long long*)(ws + 1161728); // 2,654,208 B
    unsigned int* ticket = (unsigned int*)(ws + 3815936);             //       4 B

    hipMemsetAsync(ticket, 0, sizeof(unsigned int), stream);          // ws poisoned

    rank_boxes_kernel    <<<K, 512, 0, stream>>>(rois, deltas, scores,
                                                 sbox_g, order_g, ssc_g, valid_g);
    bitmatrix_kernel     <<<K * 8, 256, 0, stream>>>(sbox_g, valid_g, supT_g);
    sweep_finalize_kernel<<<K, 256, 0, stream>>>(supT_g, order_g, ssc_g, valid_g,
                                                 rois, deltas, dists_t, ticket, out);
}

// Round 7
// 111.317 us; speedup vs baseline: 2.6403x; 1.3564x over previous
//
#include <hip/hip_runtime.h>
#include <cstdint>
#include <cstddef>

// Mask R-CNN detection post-processing, 4 stream-ordered kernels:
//   1. rank_boxes (81 x 512):  u64-key stable rank + sorted boxes + validity
//   2. bitmatrix  (648 x 256): IoU suppression bits (class x word) -> global
//   3. sweep      (81 x 64):   SINGLE-WAVE greedy sweep, rows loaded direct
//                              from global (prefetched), nz-filtered serial
//                              loop, top-300 cut, masked-score scatter
//   4. finalize   (8 x 512):   per-row max/first-argmax (redundant per block),
//                              distributed u64-key top-100 rank, output write
// Stable sorts via integer keys (softmax scores >= 0 => raw-bit monotone):
//   key = (~bits(s) << 32) | index; ascending == argsort(-s) (R5/R6-proven).
// IoU uses IEEE f32 division in reference expression order (absmax 0.0 R1-R6).
// No cooperative launch (R5: grid.sync ~ +100us); no ticket/fences (R6: the
// single-CU finalize tail serialized ~25us behind the slowest sweep block).

#define R 512
#define K 81
#define IM_W_MAX 1332.0f   // IM_W - 1
#define IM_H_MAX 799.0f    // IM_H - 1
#define XFORM_CLIP_F 4.135166556742356f  // log(1000/16)
#define NMS_THRESH_F 0.5f
#define SCORE_THRESH_F 0.001f
#define MAX_PER_IMG 100
#define POST_NMS_TOPN 300

// Box transform for (roi r, class k). Value-identical to R1-R6 (absmax 0.0).
__device__ __forceinline__ float4 transform_box(const float* __restrict__ rois,
                                                const float* __restrict__ deltas,
                                                int r, int k) {
    float4 roi = ((const float4*)rois)[r];
    float4 d4  = *(const float4*)(deltas + (size_t)r * (4 * K) + 4 * k);
    float w  = roi.z - roi.x + 1.0f;
    float h  = roi.w - roi.y + 1.0f;
    float cx = roi.x + 0.5f * w;
    float cy = roi.y + 0.5f * h;
    float dx = d4.x / 10.0f;                       // WX
    float dy = d4.y / 10.0f;                       // WY
    float dw = fminf(d4.z / 5.0f, XFORM_CLIP_F);   // WW
    float dh = fminf(d4.w / 5.0f, XFORM_CLIP_F);   // WH
    float pcx = dx * w + cx;
    float pcy = dy * h + cy;
    float pw  = expf(dw) * w;
    float ph  = expf(dh) * h;
    float4 b;
    b.x = fminf(fmaxf(pcx - 0.5f * pw, 0.0f), IM_W_MAX);
    b.y = fminf(fmaxf(pcy - 0.5f * ph, 0.0f), IM_H_MAX);
    b.z = fminf(fmaxf(pcx + 0.5f * pw - 1.0f, 0.0f), IM_W_MAX);
    b.w = fminf(fmaxf(pcy + 0.5f * ph - 1.0f, 0.0f), IM_H_MAX);
    return b;
}

// ---------------------------------------------------------------------------
// 1. Per-class u64-key stable rank + sorted boxes/scores + validity (R6-proven).
// ---------------------------------------------------------------------------
__global__ void __launch_bounds__(512)
rank_boxes_kernel(const float* __restrict__ rois,
                  const float* __restrict__ deltas,
                  const float* __restrict__ scores,
                  float4* __restrict__ sbox_g,     // [K][R] sorted boxes
                  int* __restrict__ order_g,       // [K][R] order[rank]=orig
                  float* __restrict__ ssc_g,       // [K][R] sorted scores
                  int* __restrict__ valid_g) {     // [K]
    const int k = blockIdx.x, tid = threadIdx.x;
    __shared__ unsigned long long s_key[R];        // 4 KB
    __shared__ float s_red[R];                     // 2 KB

    const float sc = scores[tid * K + k];          // strided, L2-resident
    {
        unsigned int bits = __float_as_uint(sc);   // sc >= 0: bits monotone
        s_key[tid] = ((unsigned long long)(~bits) << 32) | (unsigned int)tid;
    }
    s_red[tid] = sc;
    __syncthreads();
    for (int s = 256; s > 0; s >>= 1) {
        if (tid < s) s_red[tid] = fmaxf(s_red[tid], s_red[tid + s]);
        __syncthreads();
    }
    const bool valid = (k != 0) && (s_red[0] > SCORE_THRESH_F);  // uniform
    if (tid == 0) valid_g[k] = valid;
    if (!valid) return;

    const unsigned long long ki = s_key[tid];
    int cnt = 0;                                   // exact stable rank
    const ulonglong2* kp = (const ulonglong2*)s_key;  // uniform j2 -> broadcast
    #pragma unroll 8
    for (int j2 = 0; j2 < R / 2; ++j2) {
        ulonglong2 k2 = kp[j2];
        cnt += (k2.x < ki);
        cnt += (k2.y < ki);
    }
    sbox_g[k * R + cnt]  = transform_box(rois, deltas, tid, k);
    order_g[k * R + cnt] = tid;
    ssc_g[k * R + cnt]   = sc;
}

// ---------------------------------------------------------------------------
// 2. Bitmatrix (R6-proven): block = (class k, word w). supT_g[k][w][i] bit jj
//    set iff j = w*64+jj > i and IoU(i,j) > 0.5 (sorted order).
// ---------------------------------------------------------------------------
__global__ void __launch_bounds__(256)
bitmatrix_kernel(const float4* __restrict__ sbox_g,
                 const int* __restrict__ valid_g,
                 unsigned long long* __restrict__ supT_g) {
    const int b = blockIdx.x;
    const int k = b >> 3;
    const int w = b & 7;
    const int tid = threadIdx.x;
    if (!valid_g[k]) return;       // sweep exits for invalid k too

    __shared__ float4 s_sbox[R];   // 8 KB
    __shared__ float  s_area[R];   // 2 KB
    for (int i = tid; i < R; i += 256) {
        float4 bx = sbox_g[k * R + i];
        s_sbox[i] = bx;
        s_area[i] = (bx.z - bx.x + 1.0f) * (bx.w - bx.y + 1.0f);
    }
    __syncthreads();

    const int jbase = w * 64;
    #pragma unroll
    for (int rep = 0; rep < 2; ++rep) {
        const int i = tid + rep * 256;
        const int d = i - jbase;   // bits jj <= d are j <= i: masked out
        unsigned long long mask =
            (d < 0) ? ~0ull : ((d >= 63) ? 0ull : (~0ull << (d + 1)));
        unsigned long long bits = 0ull;
        if (mask) {                // wave-uniform skip for fully-past waves
            const float4 bi = s_sbox[i];
            const float  ai = s_area[i];
            #pragma unroll 8
            for (int jj = 0; jj < 64; ++jj) {
                float4 bj = s_sbox[jbase + jj];   // broadcast LDS read
                float  aj = s_area[jbase + jj];
                float xx1 = fmaxf(bi.x, bj.x);
                float yy1 = fmaxf(bi.y, bj.y);
                float xx2 = fminf(bi.z, bj.z);
                float yy2 = fminf(bi.w, bj.w);
                float iw = fmaxf(xx2 - xx1 + 1.0f, 0.0f);
                float ih = fmaxf(yy2 - yy1 + 1.0f, 0.0f);
                float inter = iw * ih;
                float iou = inter / (ai + aj - inter);   // IEEE div, ref order
                bits |= (unsigned long long)(iou > NMS_THRESH_F) << jj;
            }
        }
        supT_g[k * 4096 + w * 512 + i] = bits & mask;    // coalesced u64 write
    }
}

// ---------------------------------------------------------------------------
// 3. Sweep: ONE WAVE per class. Rows loaded direct from global (prefetched,
//    coalesced); nz-filtered serial greedy; top-300 cut; register scatter.
// ---------------------------------------------------------------------------
__global__ void __launch_bounds__(64)
sweep_kernel(const unsigned long long* __restrict__ supT_g,
             const int* __restrict__ order_g,
             const float* __restrict__ ssc_g,
             const int* __restrict__ valid_g,
             float* __restrict__ dists_t) {       // [K][R]
    const int k = blockIdx.x;
    const int l = threadIdx.x;                    // lane 0..63

    if (!valid_g[k]) {
        #pragma unroll
        for (int p = 0; p < 8; ++p) dists_t[k * R + p * 64 + l] = 0.0f;
        return;
    }

    // Prefetch scatter data (overlaps the sweep).
    int   ord[8];
    float ssc[8];
    #pragma unroll
    for (int p = 0; p < 8; ++p) {
        ord[p] = order_g[k * R + p * 64 + l];
        ssc[p] = ssc_g[k * R + p * 64 + l];
    }

    const unsigned long long* base = supT_g + (size_t)k * 4096;
    unsigned long long rrow[8], rnext[8];
    #pragma unroll
    for (int w = 0; w < 8; ++w) rrow[w] = base[w * 512 + l];   // wb=0 rows

    unsigned long long kb[8];
    #pragma unroll
    for (int w = 0; w < 8; ++w) kb[w] = ~0ull;

    #pragma unroll
    for (int wb = 0; wb < 8; ++wb) {
        // Prefetch next wb's rows (words < wb+1 are all-zero by construction).
        if (wb < 7) {
            #pragma unroll
            for (int w = 0; w < 8; ++w)
                rnext[w] = (w > wb) ? base[w * 512 + (wb + 1) * 64 + l] : 0ull;
        }

        // Intra-block greedy: only lanes with nonzero rows can change state
        // (row==0 => cur&=~0 is a no-op), so restrict m to them — exact.
        const unsigned long long nz = __ballot(rrow[wb] != 0ull);
        unsigned long long cur = kb[wb];
        unsigned long long m = cur & nz;
        while (m) {                    // wave-uniform serial sweep
            int bit = __builtin_ctzll(m);
            const unsigned int r_lo = (unsigned int)(rrow[wb] & 0xffffffffull);
            const unsigned int r_hi = (unsigned int)(rrow[wb] >> 32);
            unsigned long long row =
                ((unsigned long long)(unsigned int)__builtin_amdgcn_readlane((int)r_hi, bit) << 32) |
                 (unsigned long long)(unsigned int)__builtin_amdgcn_readlane((int)r_lo, bit);
            m &= m - 1;
            cur &= ~row;
            m   &= ~row;
        }
        kb[wb] = cur;

        // Inter-block pruning: OR of kept rows' future words (ballot-guarded).
        #pragma unroll
        for (int w = wb + 1; w < 8; ++w) {
            unsigned long long contrib = ((cur >> l) & 1ull) ? rrow[w] : 0ull;
            if (__ballot(contrib != 0ull)) {
                #pragma unroll
                for (int off = 32; off > 0; off >>= 1)
                    contrib |= __shfl_xor(contrib, off, 64);
                kb[w] &= ~contrib;
            }
        }

        #pragma unroll
        for (int w = 0; w < 8; ++w) rrow[w] = rnext[w];
    }

    // cumsum(keep) <= 300 cut, sorted-rank order (uniform, lane-redundant).
    int total = 0;
    #pragma unroll
    for (int w = 0; w < 8; ++w) total += __popcll(kb[w]);
    if (total > POST_NMS_TOPN) {
        int cnt = 0;
        #pragma unroll
        for (int w = 0; w < 8; ++w) {
            int pc = __popcll(kb[w]);
            if (cnt + pc <= POST_NMS_TOPN) { cnt += pc; continue; }
            unsigned long long word = kb[w], outw = 0ull;
            int room = POST_NMS_TOPN - cnt;
            while (room > 0) {
                unsigned long long lsb = word & (~word + 1ull);
                outw |= lsb; word ^= lsb; --room;
            }
            kb[w] = outw; cnt = POST_NMS_TOPN;
        }
    }

    // Scatter masked scores back to original index order.
    #pragma unroll
    for (int p = 0; p < 8; ++p)
        dists_t[k * R + ord[p]] = ((kb[p] >> l) & 1ull) ? ssc[p] : 0.0f;
}

// ---------------------------------------------------------------------------
// 4. Finalize: 8 blocks. Each block computes scores_pre/argmax for ALL 512
//    rois (coalesced, redundant), then ranks its own 64 rois with 8 threads
//    per roi + segmented shfl_xor sum. Exactly 100 winners write the output.
//    Output (700 floats): [0..499] out(100x5), [500..599] labels, [600..699] top.
// ---------------------------------------------------------------------------
__global__ void __launch_bounds__(512)
finalize_kernel(const float* __restrict__ dists_t,
                const float* __restrict__ rois,
                const float* __restrict__ deltas,
                float* __restrict__ out) {
    const int b = blockIdx.x;      // 0..7 -> rois [b*64, b*64+64)
    const int t = threadIdx.x;
    __shared__ unsigned long long s_key[R];   // 4 KB
    __shared__ int s_arg[R];                  // 2 KB

    // Phase A: per-roi max/first-argmax over K classes (coalesced reads).
    {
        const int r = t;
        float vmax = dists_t[r];   // kk = 0 column (always zeros)
        int arg = 0;
        #pragma unroll 8
        for (int kk = 1; kk < K; ++kk) {
            float v = dists_t[kk * R + r];
            if (v > vmax) { vmax = v; arg = kk; }   // first-occurrence argmax
        }
        unsigned int bits = __float_as_uint(vmax);  // vmax >= 0
        s_key[r] = ((unsigned long long)(~bits) << 32) | (unsigned int)r;
        s_arg[r] = arg;
    }
    __syncthreads();

    // Phase B: rank this block's 64 rois. 8 threads/roi, 64 keys each;
    // chunk-rotated index avoids 8-way bank conflicts; order-free sum.
    const int ri = b * 64 + (t >> 3);
    const int c  = t & 7;
    const unsigned long long ki = s_key[ri];
    int cnt = 0;
    #pragma unroll 8
    for (int j = 0; j < 64; ++j) {
        int jj = (j + c * 8) & 63;
        cnt += (s_key[c * 64 + jj] < ki);
    }
    cnt += __shfl_xor(cnt, 1, 64);     // sum within the 8-lane segment
    cnt += __shfl_xor(cnt, 2, 64);
    cnt += __shfl_xor(cnt, 4, 64);

    if (c == 0 && cnt < MAX_PER_IMG) { // exactly 100 winners grid-wide
        float vmax = __uint_as_float(~(unsigned int)(ki >> 32));
        int arg = s_arg[ri];
        bool valid = vmax > SCORE_THRESH_F;
        float4 bx = transform_box(rois, deltas, ri, arg);
        out[cnt * 5 + 0] = valid ? vmax : 0.0f;
        out[cnt * 5 + 1] = valid ? bx.x : 0.0f;
        out[cnt * 5 + 2] = valid ? bx.y : 0.0f;
        out[cnt * 5 + 3] = valid ? bx.z : 0.0f;
        out[cnt * 5 + 4] = valid ? bx.w : 0.0f;
        out[500 + cnt] = (float)arg;   // labels_all
        out[600 + cnt] = (float)ri;    // top
    }
}

// ---------------------------------------------------------------------------
extern "C" void kernel_launch(void* const* d_in, const int* in_sizes, int n_in,
                              void* d_out, int out_size, void* d_ws, size_t ws_size,
                              hipStream_t stream) {
    const float* rois   = (const float*)d_in[0];   // [512,4]
    const float* deltas = (const float*)d_in[1];   // [512,324]
    const float* scores = (const float*)d_in[2];   // [512,81]
    float* out = (float*)d_out;                    // 700 floats

    char* ws = (char*)d_ws;                        // ~3.7 MB used
    float4* sbox_g  = (float4*)(ws + 0);                              // 663,552 B
    int*    order_g = (int*)   (ws + 663552);                         // 165,888 B
    float*  ssc_g   = (float*) (ws + 829440);                         // 165,888 B
    int*    valid_g = (int*)   (ws + 995328);                         //     512 B
    float*  dists_t = (float*) (ws + 995840);                         // 165,888 B
    unsigned long long* supT_g = (unsigned long long*)(ws + 1161728); // 2,654,208 B

    rank_boxes_kernel<<<K, 512, 0, stream>>>(rois, deltas, scores,
                                             sbox_g, order_g, ssc_g, valid_g);
    bitmatrix_kernel <<<K * 8, 256, 0, stream>>>(sbox_g, valid_g, supT_g);
    sweep_kernel     <<<K, 64, 0, stream>>>(supT_g, order_g, ssc_g, valid_g, dists_t);
    finalize_kernel  <<<8, 512, 0, stream>>>(dists_t, rois, deltas, out);
}